// Round 16
// baseline (118.850 us; speedup 1.0000x reference)
//
#include <hip/hip_runtime.h>

#define B_   16
#define T_   2500
#define X_   512
#define XT   32
#define SEGS 4
#define SEGR 640
#define NSX  (X_ / XT)            // 16
#define NBLK (B_ * SEGS * NSX)    // 1024 = 4 blocks/CU exactly
#define RING 18

typedef __attribute__((ext_vector_type(4))) float f32x4;

// lgkm-only barrier (verified r9): LDS producer->consumer visibility without
// draining vmcnt; prefetched global loads stay in flight across it.
__device__ __forceinline__ void barrier_lgkm() {
    asm volatile("s_waitcnt lgkmcnt(0)\n\ts_barrier" ::: "memory");
}

// Round-16 = r9's pipeline with PB replaced by a REGISTER pipeline stage:
//  - producer period it: (1) xconv MFMA of chunk it-1 from bfP[5] registers
//    (memory-independent -> period starts issuing immediately, r9's key
//    property restored; r15 lost it and regressed), (2) products(it) from
//    loads issued at it-1 (vmcnt satisfied ~1 period ago), bfP <- new,
//    (3) prefetch chunk it+1 (flies across the lgkm barrier).
//  - fragment-direct loads (r15-refchecked): lane loads row ln16, cols
//    x0-8+16*p01+8g..+7 (2 float4 each of x,y) = exactly its MFMA B-fragment;
//    per-wave 16-col output half (p01) with 16-col staging overlap.
//  - DS ops/block-period 80 -> 50 (PB's 10 writes + 5 reads per producer wave
//    deleted); LDS 36.9 -> 24.5 KB; ring/consumer/DPP all r9 verbatim.
//  - register ktables (r14/r15-refchecked), XCD swizzle, 1024-block grid.
__global__ __launch_bounds__(256, 4) void coh16(const float* __restrict__ xg,
                                                const float* __restrict__ yg,
                                                float* __restrict__ partial)
{
    __shared__ unsigned long long XS[RING][5][34];   // 24480 B fp8 ring
    __shared__ float wred[4];

    const int tid  = threadIdx.x;
    const int lane = tid & 63;
    const int w    = tid >> 6;
    const int g    = lane >> 4;
    const int ln16 = lane & 15;
    const int pair = w >> 1;
    const int p01  = w & 1;

    // ---- XCD-aware bijective block swizzle (1024 % 8 == 0) ----
    const int bid = blockIdx.x;
    const int wid = (bid & 7) * (NBLK / 8) + (bid >> 3);
    const int xt  = wid & 15;
    const int seg = (wid >> 4) & 3;
    const int b   = wid >> 6;

    const int x0    = xt * XT;
    const int t0    = seg * SEGR;
    const int t_end = min(t0 + SEGR, T_);
    const int nm    = (t_end - t0 + 15) >> 4;
    const int pmax  = nm + 8;

    const float* xb = xg + (size_t)b * T_ * X_;
    const float* yb = yg + (size_t)b * T_ * X_;

    float local = 0.f;

    if (pair == 0) {
        // ===================== producer =====================
        float ksx = 0.f;
#pragma unroll 1
        for (int i = 0; i < 11; ++i) { float d = (float)(i - 5); ksx += expf(-d * d * (1.f / 242.f)); }
        const float scx = 16.f / ksx;
        // A_x[m][k] = kx[k-m-3]*16 fp8; m = ln16, k = 8g+sl (r4-verified)
        long a_x;
        {
            float vv[8];
#pragma unroll
            for (int sl = 0; sl < 8; ++sl) {
                int idx = 8 * g + sl - ln16 - 3;
                float d = (float)(idx - 5);
                vv[sl] = (idx >= 0 && idx <= 10) ? expf(-d * d * (1.f / 242.f)) * scx : 0.f;
            }
            int lo = __builtin_amdgcn_cvt_pk_fp8_f32(vv[0], vv[1], 0, false);
            lo     = __builtin_amdgcn_cvt_pk_fp8_f32(vv[2], vv[3], lo, true);
            int hi = __builtin_amdgcn_cvt_pk_fp8_f32(vv[4], vv[5], 0, false);
            hi     = __builtin_amdgcn_cvt_pk_fp8_f32(vv[6], vv[7], hi, true);
            a_x = (long)(((unsigned long long)(unsigned)hi << 32) | (unsigned)lo);
        }
        // DPP 4x4 byte-transpose constants (verified r5-r15)
        const uint sel1  = (ln16 & 1) ? 0x07030602u : 0x01050004u;
        const uint sel2  = (ln16 & 2) ? 0x07060302u : 0x01000504u;
        const int  cidx  = ((ln16 & 1) << 1) | ((ln16 >> 1) & 1);
        const int  abyte = (ln16 & 4);
        const int  uhalf = (ln16 >> 3);

        // fragment-direct load cols (r15-refchecked): all-in or all-out of range
        const int  c0  = x0 - 8 + 16 * p01 + 8 * g;
        const bool okC = ((unsigned)c0) < (unsigned)X_;
        const float4 z4 = make_float4(0.f, 0.f, 0.f, 0.f);

        float4 xv0, xv1, yv0, yv1;
        auto issue = [&](int c) {
            const int rowlo = t0 - 56 + 16 * c;
            const int tau   = rowlo + ln16;
            const float* xr = xb + (size_t)tau * X_ + c0;
            const float* yr = yb + (size_t)tau * X_ + c0;
            if (rowlo >= 0 && rowlo + 15 < T_) {          // fast: all rows in-bounds
                xv0 = okC ? *(const float4*)(xr)     : z4;
                xv1 = okC ? *(const float4*)(xr + 4) : z4;
                yv0 = okC ? *(const float4*)(yr)     : z4;
                yv1 = okC ? *(const float4*)(yr + 4) : z4;
            } else {                                      // guarded (seg edges)
                bool ok = okC && (tau >= 0) && (tau < T_);
                xv0 = ok ? *(const float4*)(xr)     : z4;
                xv1 = ok ? *(const float4*)(xr + 4) : z4;
                yv0 = ok ? *(const float4*)(yr)     : z4;
                yv1 = ok ? *(const float4*)(yr + 4) : z4;
            }
        };
        issue(0);   // prologue: loads for chunk 0

        long bfP[5];
#pragma unroll
        for (int f = 0; f < 5; ++f) bfP[f] = 0;

        int gb = 0;   // (2*it) % 18
        for (int it = 0; it <= pmax; ++it) {
            // ---- (1) xconv MFMA of chunk it-1 from bfP (registers, no mem dep)
            //      -> DPP transpose -> ring slots gb+16, gb+17 (r9 schedule) ----
            if (it >= 1 && it <= nm + 7) {
                int u0 = gb + 16; if (u0 >= RING) u0 -= RING;   // even <= 16
                const int uu = u0 + uhalf;
#pragma unroll
                for (int f = 0; f < 5; ++f) {
                    f32x4 z; z[0] = 0.f; z[1] = 0.f; z[2] = 0.f; z[3] = 0.f;
                    f32x4 d = __builtin_amdgcn_mfma_f32_16x16x32_fp8_fp8(a_x, bfP[f], z, 0, 0, 0);
                    int pk = __builtin_amdgcn_cvt_pk_fp8_f32(d[0], d[1], 0, false);
                    pk     = __builtin_amdgcn_cvt_pk_fp8_f32(d[2], d[3], pk, true);
                    uint pkc   = (uint)pk;
                    uint part1 = (uint)__builtin_amdgcn_update_dpp(0, (int)pkc, 177, 0xF, 0xF, true);
                    uint s1v   = __builtin_amdgcn_perm(pkc, part1, sel1);
                    uint part2 = (uint)__builtin_amdgcn_update_dpp(0, (int)s1v, 78, 0xF, 0xF, true);
                    uint Tt    = __builtin_amdgcn_perm(s1v, part2, sel2);
                    *(uint*)((uchar*)&XS[uu][f][16 * p01 + 4 * g + cidx] + abyte) = Tt;
                }
            }
            // ---- (2) products of chunk it (loads issued one period ago) -> bfP ----
            if (it <= nm + 6) {
                float xa[8] = {xv0.x, xv0.y, xv0.z, xv0.w, xv1.x, xv1.y, xv1.z, xv1.w};
                float ya[8] = {yv0.x, yv0.y, yv0.z, yv0.w, yv1.x, yv1.y, yv1.z, yv1.w};
                float p2[8], p3[8], p4[8];
#pragma unroll
                for (int i = 0; i < 8; ++i) { p2[i] = xa[i] * xa[i]; p3[i] = ya[i] * ya[i]; p4[i] = xa[i] * ya[i]; }
                auto pack8 = [](const float* v) -> long {
                    int lo = __builtin_amdgcn_cvt_pk_fp8_f32(v[0], v[1], 0, false);
                    lo     = __builtin_amdgcn_cvt_pk_fp8_f32(v[2], v[3], lo, true);
                    int hi = __builtin_amdgcn_cvt_pk_fp8_f32(v[4], v[5], 0, false);
                    hi     = __builtin_amdgcn_cvt_pk_fp8_f32(v[6], v[7], hi, true);
                    return (long)(((unsigned long long)(unsigned)hi << 32) | (unsigned)lo);
                };
                bfP[0] = pack8(xa); bfP[1] = pack8(ya);
                bfP[2] = pack8(p2); bfP[3] = pack8(p3); bfP[4] = pack8(p4);
                // ---- (3) prefetch chunk it+1 (flies across the raw barrier) ----
                if (it + 1 <= nm + 6) issue(it + 1);
            }
            barrier_lgkm();
            gb += 2; if (gb >= RING) gb -= RING;
        }
    } else {
        // ===================== consumer (r9 verbatim, register ktable) =====================
        float kst = 0.f;
#pragma unroll 1
        for (int i = 0; i < 101; ++i) { float d = (float)(i - 50); kst += expf(-d * d * (1.f / 882.f)); }
        const float sct = 16.f / kst;
        // A_t[c][m][k] = kt[32c+k-m-6]*16 fp8 (r4-verified)
        long a_t[4];
#pragma unroll
        for (int c = 0; c < 4; ++c) {
            float vv[8];
#pragma unroll
            for (int sl = 0; sl < 8; ++sl) {
                int idx = 32 * c + 8 * g + sl - ln16 - 6;
                float d = (float)(idx - 50);
                vv[sl] = (idx >= 0 && idx <= 100) ? expf(-d * d * (1.f / 882.f)) * sct : 0.f;
            }
            int lo = __builtin_amdgcn_cvt_pk_fp8_f32(vv[0], vv[1], 0, false);
            lo     = __builtin_amdgcn_cvt_pk_fp8_f32(vv[2], vv[3], lo, true);
            int hi = __builtin_amdgcn_cvt_pk_fp8_f32(vv[4], vv[5], 0, false);
            hi     = __builtin_amdgcn_cvt_pk_fp8_f32(vv[6], vv[7], hi, true);
            a_t[c] = (long)(((unsigned long long)(unsigned)hi << 32) | (unsigned)lo);
        }

        int gb = 0;   // (2*it) % 18; strip m = it-9 reads slots gb .. gb+15
        for (int it = 0; it <= pmax; ++it) {
            if (it >= 9) {
                const int m = it - 9;
                f32x4 acc[5];
#pragma unroll
                for (int f = 0; f < 5; ++f) { acc[f][0] = 0.f; acc[f][1] = 0.f; acc[f][2] = 0.f; acc[f][3] = 0.f; }
#pragma unroll
                for (int c = 0; c < 4; ++c) {
                    int u = gb + 4 * c + g; if (u >= RING) u -= RING;   // slot of group 2m+4c+g
#pragma unroll
                    for (int f = 0; f < 5; ++f) {
                        long bfrag = (long)XS[u][f][16 * p01 + ln16];
                        acc[f] = __builtin_amdgcn_mfma_f32_16x16x32_fp8_fp8(a_t[c], bfrag, acc[f], 0, 0, 0);
                    }
                }
                const float s_ = 1.f / 256.f;   // undo kt(16)*kx(16) scaling
                if (16 * m + 15 < t_end - t0) { // fast: whole strip valid
#pragma unroll
                    for (int r = 0; r < 4; ++r) {
                        float a0 = acc[0][r], a1 = acc[1][r];
                        float sa0 = a0 * s_, sa1 = a1 * s_;
                        float cov = fmaf(-sa0, a1, acc[4][r]);
                        float vx  = fmaf(-sa0, a0, acc[2][r]);
                        float vy  = fmaf(-sa1, a1, acc[3][r]);
                        local += 1.0f - cov * rsqrtf(fmaf(vx, vy, 6.5536e-5f));
                    }
                } else {                         // guarded (last strip of seg 3)
#pragma unroll
                    for (int r = 0; r < 4; ++r) {
                        int t = t0 + 16 * m + 4 * g + r;
                        if (t < t_end) {
                            float a0 = acc[0][r], a1 = acc[1][r];
                            float sa0 = a0 * s_, sa1 = a1 * s_;
                            float cov = fmaf(-sa0, a1, acc[4][r]);
                            float vx  = fmaf(-sa0, a0, acc[2][r]);
                            float vy  = fmaf(-sa1, a1, acc[3][r]);
                            local += 1.0f - cov * rsqrtf(fmaf(vx, vy, 6.5536e-5f));
                        }
                    }
                }
            }
            barrier_lgkm();
            gb += 2; if (gb >= RING) gb -= RING;
        }
    }

    // ---- block reduction ----
#pragma unroll
    for (int off = 32; off >= 1; off >>= 1) local += __shfl_down(local, off);
    if ((tid & 63) == 0) wred[tid >> 6] = local;
    __syncthreads();
    if (tid == 0)
        partial[wid] = wred[0] + wred[1] + wred[2] + wred[3];
}

__global__ __launch_bounds__(256) void coh_reduce(const float* __restrict__ partial,
                                                  float* __restrict__ out) {
    __shared__ float wred[4];
    const int tid = threadIdx.x;
    float s = 0.0f;
    for (int i = tid; i < NBLK; i += 256) s += partial[i];
#pragma unroll
    for (int off = 32; off >= 1; off >>= 1) s += __shfl_down(s, off);
    if ((tid & 63) == 0) wred[tid >> 6] = s;
    __syncthreads();
    if (tid == 0)
        out[0] = (wred[0] + wred[1] + wred[2] + wred[3]) *
                 (1.0f / ((float)B_ * (float)T_ * (float)X_));
}

extern "C" void kernel_launch(void* const* d_in, const int* in_sizes, int n_in,
                              void* d_out, int out_size, void* d_ws, size_t ws_size,
                              hipStream_t stream) {
    const float* x = (const float*)d_in[0];
    const float* y = (const float*)d_in[1];
    float* out = (float*)d_out;
    float* partial = (float*)d_ws;   // NBLK floats = 4 KB

    coh16<<<dim3(NBLK), 256, 0, stream>>>(x, y, partial);
    coh_reduce<<<1, 256, 0, stream>>>(partial, out);
}

// Round 17
// 61.818 us; speedup vs baseline: 1.9226x; 1.9226x over previous
//
#include <hip/hip_runtime.h>
#include <hip/hip_bf16.h>

#define B_   16
#define T_   2500
#define X_   512
#define XT   32
#define SEGS 4
#define SEGR 640
#define NSX  (X_ / XT)            // 16
#define NBLK (B_ * SEGS * NSX)    // 1024

typedef __attribute__((ext_vector_type(4))) float f32x4;

// Raw barrier: drain LDS (lgkmcnt) only, leave global loads (vmcnt) in flight.
// Single asm block so the wait and the barrier cannot be separated; "memory"
// clobber orders all LDS/global memory *operations* across it while letting
// issued loads complete later (compiler inserts vmcnt at first register use).
__device__ __forceinline__ void barrier_lgkm() {
    asm volatile("s_waitcnt lgkmcnt(0)\n\ts_barrier" ::: "memory");
}

// Round-17 = round-9 restored byte-for-byte (best measured: 61.49 us).
// r10-r16 falsified, in order: phase-split (+53%), role-mix/lag-2/pre-gather
// (null), 5-blocks/CU via private-row xconv (+46%), barrier-free wave-private
// (+210%), 2-chunk periods (+64%), PB-less fragment-direct loads (+87%, the
// r15/r16 regression root cause: 16-rows-per-instruction scatter vs r9's
// 256B-contiguous staging). r9's PB is load-coalescer + transpose + pipeline
// register in one; the structure is latency/skew-bound with no saturated pipe
// and is the empirical local optimum of this design family.
__global__ __launch_bounds__(256, 4) void coh9(const float* __restrict__ xg,
                                               const float* __restrict__ yg,
                                               float* __restrict__ partial)
{
    __shared__ float ktn[104];
    __shared__ float kxn[12];
    __shared__ float norm2[2];
    __shared__ unsigned long long XS[18][5][34];    // fp8 ring: byte rs of [slot][f][col] = row-slot
    __shared__ unsigned long long PBq[2][5][16][9]; // fp8 products ping-pong; 72B rows
    __shared__ float wred[4];

    const int tid  = threadIdx.x;
    const int lane = tid & 63;
    const int w    = tid >> 6;
    const int g    = lane >> 4;
    const int ln16 = lane & 15;
    const int pair = w >> 1;
    const int p01  = w & 1;

    // ---- XCD-aware bijective block swizzle (1024 blocks, 8 XCDs) ----
    const int bid = blockIdx.x;
    const int wid = (bid & 7) * (NBLK / 8) + (bid >> 3);
    const int xt  = wid & 15;
    const int seg = (wid >> 4) & 3;
    const int b   = wid >> 6;

    const int x0    = xt * XT;
    const int t0    = seg * SEGR;
    const int t_end = min(t0 + SEGR, T_);
    const int nm    = (t_end - t0 + 15) >> 4;
    const int itmax = nm + 8;

    // ---- normalized Gaussian tables ----
    if (tid < 104) ktn[tid] = 0.0f;
    if (tid < 12)  kxn[tid] = 0.0f;
    __syncthreads();
    if (tid < 101) { float d = (float)(tid - 50); ktn[tid] = expf(-d * d / (2.0f * 21.0f * 21.0f)); }
    if (tid < 11)  { float d = (float)(tid - 5);  kxn[tid] = expf(-d * d / (2.0f * 11.0f * 11.0f)); }
    __syncthreads();
    if (tid == 0) {
        float s = 0.f; for (int i = 0; i < 101; ++i) s += ktn[i]; norm2[0] = 1.0f / s;
        s = 0.f;       for (int i = 0; i < 11;  ++i) s += kxn[i]; norm2[1] = 1.0f / s;
    }
    __syncthreads();
    if (tid < 101) ktn[tid] *= norm2[0];
    if (tid < 11)  kxn[tid] *= norm2[1];
    __syncthreads();

    const float* xb = xg + (size_t)b * T_ * X_;
    const float* yb = yg + (size_t)b * T_ * X_;

    float local = 0.f;

    if (pair == 0) {
        // ===================== producer loop =====================
        long a_x;
        {
            float vv[8];
#pragma unroll
            for (int sl = 0; sl < 8; ++sl) {
                int idx = 8 * g + sl - ln16 - 3;
                vv[sl] = (idx >= 0 && idx <= 10) ? kxn[idx] * 16.0f : 0.0f;
            }
            int lo = __builtin_amdgcn_cvt_pk_fp8_f32(vv[0], vv[1], 0, false);
            lo     = __builtin_amdgcn_cvt_pk_fp8_f32(vv[2], vv[3], lo, true);
            int hi = __builtin_amdgcn_cvt_pk_fp8_f32(vv[4], vv[5], 0, false);
            hi     = __builtin_amdgcn_cvt_pk_fp8_f32(vv[6], vv[7], hi, true);
            a_x = (long)(((unsigned long long)(unsigned)hi << 32) | (unsigned)lo);
        }
        // DPP 4x4 byte-transpose constants (verified r5-r8)
        const uint sel1  = (ln16 & 1) ? 0x07030602u : 0x01050004u;
        const uint sel2  = (ln16 & 2) ? 0x07060302u : 0x01000504u;
        const int  cidx  = ((ln16 & 1) << 1) | ((ln16 >> 1) & 1);
        const int  abyte = (ln16 & 4);
        const int  uhalf = (ln16 >> 3);

        const int  gcol  = x0 - 16 + 4 * ln16;
        const bool colOK = (gcol >= 0) && (gcol < X_);

        float4 xv[2], yv[2];
        // prologue: issue loads for chunk 0
#pragma unroll
        for (int s = 0; s < 2; ++s) {
            int grow = t0 - 56 + 8 * p01 + 4 * s + g;
            bool ok = colOK && (grow >= 0) && (grow < T_);
            xv[s] = ok ? *(const float4*)(xb + (size_t)grow * X_ + gcol) : make_float4(0.f, 0.f, 0.f, 0.f);
            yv[s] = ok ? *(const float4*)(yb + (size_t)grow * X_ + gcol) : make_float4(0.f, 0.f, 0.f, 0.f);
        }

        int gbase = 0;
        for (int it = 0; it <= itmax; ++it) {
            // ---- xconv-MFMA of chunk it-1 -> ring (loads for it keep flying) ----
            if (it >= 1 && it <= nm + 7) {
                int u0 = gbase + 16; if (u0 >= 18) u0 -= 18;
                int u1 = u0 + 1;     if (u1 >= 18) u1 -= 18;
                const int uu = uhalf ? u1 : u0;
                const int sb = (it - 1) & 1;
#pragma unroll
                for (int f = 0; f < 5; ++f) {
                    long bfrag = (long)PBq[sb][f][ln16][1 + 2 * p01 + g];
                    f32x4 z; z[0] = 0.f; z[1] = 0.f; z[2] = 0.f; z[3] = 0.f;
                    f32x4 d = __builtin_amdgcn_mfma_f32_16x16x32_fp8_fp8(a_x, bfrag, z, 0, 0, 0);
                    int pk = __builtin_amdgcn_cvt_pk_fp8_f32(d[0], d[1], 0, false);
                    pk     = __builtin_amdgcn_cvt_pk_fp8_f32(d[2], d[3], pk, true);
                    uint pkc   = (uint)pk;
                    uint part1 = (uint)__builtin_amdgcn_update_dpp(0, (int)pkc, 177, 0xF, 0xF, true);
                    uint s1v   = __builtin_amdgcn_perm(pkc, part1, sel1);
                    uint part2 = (uint)__builtin_amdgcn_update_dpp(0, (int)s1v, 78, 0xF, 0xF, true);
                    uint Tt    = __builtin_amdgcn_perm(s1v, part2, sel2);
                    *(uint*)((uchar*)&XS[uu][f][16 * p01 + 4 * g + cidx] + abyte) = Tt;
                }
            }
            // ---- products of chunk it (consume loads issued one iteration ago) ----
            if (it <= nm + 6) {
                const int db = it & 1;
#pragma unroll
                for (int s = 0; s < 2; ++s) {
                    int rrs = 8 * p01 + 4 * s + g;
                    float4 X = xv[s], Y = yv[s];
                    int q0 = __builtin_amdgcn_cvt_pk_fp8_f32(X.x, X.y, 0, false);
                    q0     = __builtin_amdgcn_cvt_pk_fp8_f32(X.z, X.w, q0, true);
                    int q1 = __builtin_amdgcn_cvt_pk_fp8_f32(Y.x, Y.y, 0, false);
                    q1     = __builtin_amdgcn_cvt_pk_fp8_f32(Y.z, Y.w, q1, true);
                    int q2 = __builtin_amdgcn_cvt_pk_fp8_f32(X.x * X.x, X.y * X.y, 0, false);
                    q2     = __builtin_amdgcn_cvt_pk_fp8_f32(X.z * X.z, X.w * X.w, q2, true);
                    int q3 = __builtin_amdgcn_cvt_pk_fp8_f32(Y.x * Y.x, Y.y * Y.y, 0, false);
                    q3     = __builtin_amdgcn_cvt_pk_fp8_f32(Y.z * Y.z, Y.w * Y.w, q3, true);
                    int q4 = __builtin_amdgcn_cvt_pk_fp8_f32(X.x * Y.x, X.y * Y.y, 0, false);
                    q4     = __builtin_amdgcn_cvt_pk_fp8_f32(X.z * Y.z, X.w * Y.w, q4, true);
                    *(uint*)((uchar*)&PBq[db][0][rrs][0] + 4 * ln16) = (uint)q0;
                    *(uint*)((uchar*)&PBq[db][1][rrs][0] + 4 * ln16) = (uint)q1;
                    *(uint*)((uchar*)&PBq[db][2][rrs][0] + 4 * ln16) = (uint)q2;
                    *(uint*)((uchar*)&PBq[db][3][rrs][0] + 4 * ln16) = (uint)q3;
                    *(uint*)((uchar*)&PBq[db][4][rrs][0] + 4 * ln16) = (uint)q4;
                }
            }
            // ---- issue loads for chunk it+1 (stay in flight across the raw barrier) ----
            if (it + 1 <= nm + 6) {
#pragma unroll
                for (int s = 0; s < 2; ++s) {
                    int grow = t0 - 56 + 16 * (it + 1) + 8 * p01 + 4 * s + g;
                    bool ok = colOK && (grow >= 0) && (grow < T_);
                    xv[s] = ok ? *(const float4*)(xb + (size_t)grow * X_ + gcol) : make_float4(0.f, 0.f, 0.f, 0.f);
                    yv[s] = ok ? *(const float4*)(yb + (size_t)grow * X_ + gcol) : make_float4(0.f, 0.f, 0.f, 0.f);
                }
            }
            barrier_lgkm();
            gbase += 2; if (gbase >= 18) gbase -= 18;
        }
    } else {
        // ===================== consumer loop =====================
        long a_t[4];
#pragma unroll
        for (int c = 0; c < 4; ++c) {
            float vv[8];
#pragma unroll
            for (int sl = 0; sl < 8; ++sl) {
                int idx = 32 * c + 8 * g + sl - ln16 - 6;
                vv[sl] = (idx >= 0 && idx <= 100) ? ktn[idx] * 16.0f : 0.0f;
            }
            int lo = __builtin_amdgcn_cvt_pk_fp8_f32(vv[0], vv[1], 0, false);
            lo     = __builtin_amdgcn_cvt_pk_fp8_f32(vv[2], vv[3], lo, true);
            int hi = __builtin_amdgcn_cvt_pk_fp8_f32(vv[4], vv[5], 0, false);
            hi     = __builtin_amdgcn_cvt_pk_fp8_f32(vv[6], vv[7], hi, true);
            a_t[c] = (long)(((unsigned long long)(unsigned)hi << 32) | (unsigned)lo);
        }

        int gbase = 0;
        for (int it = 0; it <= itmax; ++it) {
            if (it >= 9) {
                const int m = it - 9;
                f32x4 acc[5];
#pragma unroll
                for (int f = 0; f < 5; ++f) { acc[f][0] = 0.f; acc[f][1] = 0.f; acc[f][2] = 0.f; acc[f][3] = 0.f; }
#pragma unroll
                for (int c = 0; c < 4; ++c) {
                    int u = gbase + 4 * c + g; if (u >= 18) u -= 18;   // slot of row-group 2m+4c+g
#pragma unroll
                    for (int f = 0; f < 5; ++f) {
                        long bfrag = (long)XS[u][f][16 * p01 + ln16];
                        acc[f] = __builtin_amdgcn_mfma_f32_16x16x32_fp8_fp8(a_t[c], bfrag, acc[f], 0, 0, 0);
                    }
                }
                const float s_ = 1.0f / 256.0f;   // undo kt(16)*kx(16) scaling
#pragma unroll
                for (int r = 0; r < 4; ++r) {
                    int t = t0 + 16 * m + 4 * g + r;
                    if (t < t_end) {
                        float a0 = acc[0][r], a1 = acc[1][r];
                        float sa0 = a0 * s_, sa1 = a1 * s_;
                        float cov = fmaf(-sa0, a1, acc[4][r]);
                        float vx  = fmaf(-sa0, a0, acc[2][r]);
                        float vy  = fmaf(-sa1, a1, acc[3][r]);
                        local += 1.0f - cov * rsqrtf(fmaf(vx, vy, 6.5536e-5f));
                    }
                }
            }
            barrier_lgkm();
            gbase += 2; if (gbase >= 18) gbase -= 18;
        }
    }

    // ---- block reduction ----
#pragma unroll
    for (int off = 32; off >= 1; off >>= 1) local += __shfl_down(local, off);
    if ((tid & 63) == 0) wred[tid >> 6] = local;
    __syncthreads();
    if (tid == 0)
        partial[wid] = wred[0] + wred[1] + wred[2] + wred[3];
}

__global__ __launch_bounds__(256) void coh_reduce(const float* __restrict__ partial,
                                                  float* __restrict__ out) {
    __shared__ float wred[4];
    const int tid = threadIdx.x;
    float s = 0.0f;
    for (int i = tid; i < NBLK; i += 256) s += partial[i];
#pragma unroll
    for (int off = 32; off >= 1; off >>= 1) s += __shfl_down(s, off);
    if ((tid & 63) == 0) wred[tid >> 6] = s;
    __syncthreads();
    if (tid == 0)
        out[0] = (wred[0] + wred[1] + wred[2] + wred[3]) *
                 (1.0f / ((float)B_ * (float)T_ * (float)X_));
}

extern "C" void kernel_launch(void* const* d_in, const int* in_sizes, int n_in,
                              void* d_out, int out_size, void* d_ws, size_t ws_size,
                              hipStream_t stream) {
    const float* x = (const float*)d_in[0];
    const float* y = (const float*)d_in[1];
    float* out = (float*)d_out;
    float* partial = (float*)d_ws;   // NBLK floats = 4 KB

    coh9<<<dim3(NBLK), 256, 0, stream>>>(x, y, partial);
    coh_reduce<<<1, 256, 0, stream>>>(partial, out);
}